// Round 1
// baseline (186.581 us; speedup 1.0000x reference)
//
#include <hip/hip_runtime.h>
#include <math.h>

// Match numpy (no FMA contraction) — mask boundary is bit-sensitive.
#pragma clang fp contract(off)

namespace {

constexpr int B = 12, H = 192, W = 640;
constexpr int HW  = H * W;        // 122880
constexpr int BHW = B * HW;       // 1474560
constexpr int NQ  = BHW / 4;      // 368640 float4 groups
constexpr float EPS = 1e-7f;

constexpr int GRID = 512;         // blocks per dispatch (grid-stride)
constexpr int TPB  = 1024;        // 16 waves/block

// ws layout: redA[GRID*4] f32 @ +0 (8 KB) | redB[GRID*2] f32 @ +8192 (4 KB) |
//            win[B*HW] u32 @ +16384 (5.90 MB)
// Winner semantics: LWW in linear index order == max-index-wins (proven bit-exact
// in the previous LDS-chunk version). Implemented directly as one global
// atomicMax(key = n_local + 1) per source pixel; 0 = no writer.
// check[] scratch lives in out[0..BHW) between kB and kC (proven pattern).

// P = (K @ pose)[:3,:] — arithmetic identical to reference einsum
// (left-assoc, contract off).
__device__ __forceinline__ void computeP(const float* __restrict__ Kb,
                                         const float* __restrict__ Po, float* P) {
#pragma unroll
    for (int i = 0; i < 3; ++i)
#pragma unroll
        for (int j = 0; j < 4; ++j) {
            float s = Kb[i*4+0] * Po[0*4+j];
            s = s + Kb[i*4+1] * Po[1*4+j];
            s = s + Kb[i*4+2] * Po[2*4+j];
            s = s + Kb[i*4+3] * Po[3*4+j];
            P[i*4+j] = s;
        }
}

__device__ __forceinline__ void static_flow_P(
    const float* __restrict__ iK, const float* __restrict__ P,
    int x, int y, float d, float& sx, float& sy)
{
    float fx = (float)x, fy = (float)y;
    float cam0 = iK[0]*fx + iK[1]*fy + iK[2];
    float cam1 = iK[4]*fx + iK[5]*fy + iK[6];
    float cam2 = iK[8]*fx + iK[9]*fy + iK[10];
    cam0 = d * cam0; cam1 = d * cam1; cam2 = d * cam2;
    float cp0 = P[0]*cam0 + P[1]*cam1 + P[2]*cam2  + P[3];
    float cp1 = P[4]*cam0 + P[5]*cam1 + P[6]*cam2  + P[7];
    float cp2 = P[8]*cam0 + P[9]*cam1 + P[10]*cam2 + P[11];
    float pz = cp2 + EPS;
    sx = cp0 / pz - fx;
    sy = cp1 / pz - fy;
}

__device__ __forceinline__ float norm01(float v, float mn, float mx) {
    return (2.0f * (v - mn)) / (mx - mn) - 1.0f;
}

// Block-wide reduce for 1024-thread blocks (16 waves) + broadcast.
__device__ __forceinline__ void blockRed4(float& a0, float& a1, float& a2, float& a3,
                                          float (*sred)[4], float* bc) {
    for (int off = 32; off; off >>= 1) {
        a0 = fminf(a0, __shfl_down(a0, off, 64));
        a1 = fmaxf(a1, __shfl_down(a1, off, 64));
        a2 = fminf(a2, __shfl_down(a2, off, 64));
        a3 = fmaxf(a3, __shfl_down(a3, off, 64));
    }
    int lane = threadIdx.x & 63, wv = threadIdx.x >> 6;
    if (lane == 0) { sred[wv][0]=a0; sred[wv][1]=a1; sred[wv][2]=a2; sred[wv][3]=a3; }
    __syncthreads();
    if (threadIdx.x == 0) {
#pragma unroll
        for (int w = 1; w < 16; ++w) {
            a0 = fminf(a0, sred[w][0]); a1 = fmaxf(a1, sred[w][1]);
            a2 = fminf(a2, sred[w][2]); a3 = fmaxf(a3, sred[w][3]);
        }
        bc[0]=a0; bc[1]=a1; bc[2]=a2; bc[3]=a3;
    }
    __syncthreads();
    a0=bc[0]; a1=bc[1]; a2=bc[2]; a3=bc[3];
}

__device__ __forceinline__ void blockRed2(float& a0, float& a1,
                                          float (*sred)[4], float* bc) {
    for (int off = 32; off; off >>= 1) {
        a0 = fminf(a0, __shfl_down(a0, off, 64));
        a1 = fmaxf(a1, __shfl_down(a1, off, 64));
    }
    int lane = threadIdx.x & 63, wv = threadIdx.x >> 6;
    if (lane == 0) { sred[wv][0]=a0; sred[wv][1]=a1; }
    __syncthreads();
    if (threadIdx.x == 0) {
#pragma unroll
        for (int w = 1; w < 16; ++w) {
            a0 = fminf(a0, sred[w][0]); a1 = fmaxf(a1, sred[w][1]);
        }
        bc[0]=a0; bc[1]=a1;
    }
    __syncthreads();
    a0=bc[0]; a1=bc[1];
}

// Dispatch 1: single pass over flow+depth — flow min/max + static-flow min/max
// partials into redA; zero the winner array in the same loop (kernel boundary
// orders the zeroing before kB's atomics).
__global__ void __launch_bounds__(TPB)
kA(const float* __restrict__ flow, const float* __restrict__ depth,
   const float* __restrict__ Km, const float* __restrict__ invK,
   const float* __restrict__ pose,
   unsigned int* __restrict__ win, float* __restrict__ redA)
{
    __shared__ float sred[16][4];
    __shared__ float bc[4];

    float fmn = INFINITY, fmx = -INFINITY, smn = INFINITY, smx = -INFINITY;
    float P[12]; int bCur = -1;
    const int stride = GRID * TPB;
    for (int g = blockIdx.x * TPB + threadIdx.x; g < NQ; g += stride) {
        int p0 = g * 4;
        int b  = p0 / HW;
        if (b != bCur) { computeP(Km + b*16, pose + b*16, P); bCur = b; }
        const float* iK = invK + b * 16;
        int n0 = p0 - b * HW;
        int y  = n0 / W;                 // quads never cross a row (W%4==0)
        int x0 = n0 - y * W;
        float4 fx4 = *(const float4*)(flow + b*2*HW + n0);
        float4 fy4 = *(const float4*)(flow + b*2*HW + HW + n0);
        float4 d4  = *(const float4*)(depth + p0);
        fmn = fminf(fmn, fminf(fminf(fx4.x, fx4.y), fminf(fx4.z, fx4.w)));
        fmx = fmaxf(fmx, fmaxf(fmaxf(fx4.x, fx4.y), fmaxf(fx4.z, fx4.w)));
        fmn = fminf(fmn, fminf(fminf(fy4.x, fy4.y), fminf(fy4.z, fy4.w)));
        fmx = fmaxf(fmx, fmaxf(fmaxf(fy4.x, fy4.y), fmaxf(fy4.z, fy4.w)));
        float da[4] = {d4.x, d4.y, d4.z, d4.w};
#pragma unroll
        for (int j = 0; j < 4; ++j) {
            float sx, sy;
            static_flow_P(iK, P, x0 + j, y, da[j], sx, sy);
            smn = fminf(smn, fminf(sx, sy));
            smx = fmaxf(smx, fmaxf(sx, sy));
        }
        *(uint4*)(win + p0) = make_uint4(0u, 0u, 0u, 0u);
    }
    blockRed4(fmn, fmx, smn, smx, sred, bc);
    if (threadIdx.x == 0) {
        redA[blockIdx.x*4+0] = fmn; redA[blockIdx.x*4+1] = fmx;
        redA[blockIdx.x*4+2] = smn; redA[blockIdx.x*4+3] = smx;
    }
}

// Dispatch 2: re-reduce redA (L2-hit) + check pass (stash check into
// out[0..BHW)) + winner scatter via global atomicMax on the flow values
// already in registers. check partial min/max -> redB.
__global__ void __launch_bounds__(TPB)
kB(const float* __restrict__ flow, const float* __restrict__ depth,
   const float* __restrict__ Km, const float* __restrict__ invK,
   const float* __restrict__ pose,
   const float* __restrict__ redA, float* __restrict__ redB,
   unsigned int* __restrict__ win, float* __restrict__ out)
{
    __shared__ float sred[16][4];
    __shared__ float bc[4];

    float gfmn = INFINITY, gfmx = -INFINITY, gsmn = INFINITY, gsmx = -INFINITY;
    for (int i = threadIdx.x; i < GRID; i += TPB) {
        gfmn = fminf(gfmn, redA[i*4+0]); gfmx = fmaxf(gfmx, redA[i*4+1]);
        gsmn = fminf(gsmn, redA[i*4+2]); gsmx = fmaxf(gsmx, redA[i*4+3]);
    }
    blockRed4(gfmn, gfmx, gsmn, gsmx, sred, bc);

    float cmn = INFINITY, cmx = -INFINITY;
    float P[12]; int bCur = -1;
    const int stride = GRID * TPB;
    for (int g = blockIdx.x * TPB + threadIdx.x; g < NQ; g += stride) {
        int p0 = g * 4;
        int b  = p0 / HW;
        if (b != bCur) { computeP(Km + b*16, pose + b*16, P); bCur = b; }
        const float* iK = invK + b * 16;
        int n0 = p0 - b * HW;
        int y  = n0 / W;
        int x0 = n0 - y * W;
        float4 fx4 = *(const float4*)(flow + b*2*HW + n0);
        float4 fy4 = *(const float4*)(flow + b*2*HW + HW + n0);
        float4 d4  = *(const float4*)(depth + p0);
        float fxa[4] = {fx4.x, fx4.y, fx4.z, fx4.w};
        float fya[4] = {fy4.x, fy4.y, fy4.z, fy4.w};
        float da[4]  = {d4.x, d4.y, d4.z, d4.w};
        unsigned int* winb = win + b * HW;
        float4 cv;
        float* cva = (float*)&cv;
#pragma unroll
        for (int j = 0; j < 4; ++j) {
            float sx, sy;
            static_flow_P(iK, P, x0 + j, y, da[j], sx, sy);
            float dx = norm01(fxa[j], gfmn, gfmx) - norm01(sx, gsmn, gsmx);
            float dy = norm01(fya[j], gfmn, gfmx) - norm01(sy, gsmn, gsmx);
            float c = sqrtf(dx*dx + dy*dy);
            cva[j] = c;
            cmn = fminf(cmn, c); cmx = fmaxf(cmx, c);
            // winner scatter: round-half-even (rintf == jnp.round), clip, max-index
            int cxi = (int)rintf((float)(x0 + j) + fxa[j]);
            int cyi = (int)rintf((float)y + fya[j]);
            cxi = min(max(cxi, 0), W - 1);
            cyi = min(max(cyi, 0), H - 1);
            atomicMax(&winb[cyi * W + cxi], (unsigned)(n0 + j + 1));
        }
        *(float4*)(out + p0) = cv;   // stash check (overwritten by kC)
    }
    blockRed2(cmn, cmx, sred, bc);
    if (threadIdx.x == 0) { redB[blockIdx.x*2] = cmn; redB[blockIdx.x*2+1] = cmx; }
}

// Dispatch 3: re-reduce redB + threshold stashed check in-place + winner
// gather (exact payloads) -> bwd_flow, seg_ref.
__global__ void __launch_bounds__(TPB)
kC(const float* __restrict__ flow, const int* __restrict__ seg,
   const float* __restrict__ redB, const unsigned int* __restrict__ win,
   float* __restrict__ out)
{
    __shared__ float sred[16][4];
    __shared__ float bc[4];

    float gcmn = INFINITY, gcmx = -INFINITY;
    for (int i = threadIdx.x; i < GRID; i += TPB) {
        gcmn = fminf(gcmn, redB[2*i]); gcmx = fmaxf(gcmx, redB[2*i+1]);
    }
    blockRed2(gcmn, gcmx, sred, bc);

    const int stride = GRID * TPB;
    for (int g = blockIdx.x * TPB + threadIdx.x; g < NQ; g += stride) {
        int p0 = g * 4;
        int b  = p0 / HW;
        int n0 = p0 - b * HW;
        float4 c4 = *(const float4*)(out + p0);     // stashed check
        uint4  w4 = *(const uint4*)(win + p0);
        const float* fb = flow + b * 2 * HW;
        const int*   sb = seg + b * HW;
        float    ca[4] = {c4.x, c4.y, c4.z, c4.w};
        unsigned wa[4] = {w4.x, w4.y, w4.z, w4.w};
        float4 m4, bx4, by4, sg4;
        float* ma  = (float*)&m4;
        float* bxa = (float*)&bx4;
        float* bya = (float*)&by4;
        float* sga = (float*)&sg4;
#pragma unroll
        for (int j = 0; j < 4; ++j) {
            float cn = (ca[j] - gcmn) / (gcmx - gcmn);
            ma[j] = (cn < 0.98f) ? 1.0f : 0.0f;
            float bx = 0.0f, by = 0.0f, sg = 0.0f;
            if (wa[j]) {
                int nw = (int)wa[j] - 1;
                bx = -fb[nw];
                by = -fb[HW + nw];
                sg = sb[nw] ? 1.0f : 0.0f;
            }
            bxa[j] = bx; bya[j] = by; sga[j] = sg;
        }
        *(float4*)(out + p0)                      = m4;   // motion_mask
        *(float4*)(out + BHW + b*2*HW + n0)       = bx4;  // bwd_flow x
        *(float4*)(out + BHW + b*2*HW + HW + n0)  = by4;  // bwd_flow y
        *(float4*)(out + 3*BHW + p0)              = sg4;  // seg_ref
    }
}

} // namespace

extern "C" void kernel_launch(void* const* d_in, const int* in_sizes, int n_in,
                              void* d_out, int out_size, void* d_ws, size_t ws_size,
                              hipStream_t stream) {
    const float* flow  = (const float*)d_in[0];
    const float* depth = (const float*)d_in[1];
    const float* Km    = (const float*)d_in[2];
    const float* invK  = (const float*)d_in[3];
    const float* pose  = (const float*)d_in[4];
    const int*   seg   = (const int*)d_in[5];
    float* out = (float*)d_out;

    float* redA = (float*)d_ws;
    float* redB = (float*)((char*)d_ws + 8192);
    unsigned int* win = (unsigned int*)((char*)d_ws + 16384);   // 5.90 MB

    kA<<<GRID, TPB, 0, stream>>>(flow, depth, Km, invK, pose, win, redA);
    kB<<<GRID, TPB, 0, stream>>>(flow, depth, Km, invK, pose, redA, redB, win, out);
    kC<<<GRID, TPB, 0, stream>>>(flow, seg, redB, win, out);
}

// Round 3
// 150.144 us; speedup vs baseline: 1.2427x; 1.2427x over previous
//
#include <hip/hip_runtime.h>
#include <math.h>

// Match numpy (no FMA contraction) — mask boundary is bit-sensitive.
#pragma clang fp contract(off)

namespace {

constexpr int B = 12, H = 192, W = 640;
constexpr int HW  = H * W;        // 122880
constexpr int BHW = B * HW;       // 1474560
constexpr int NQ  = BHW / 4;      // 368640 float4 groups
constexpr float EPS = 1e-7f;

constexpr int GRID = 512;         // check/reduce blocks (grid-stride)
constexpr int TPB  = 1024;        // 16 waves/block

constexpr int TR    = 24;         // winner-tile rows
constexpr int TILES = H / TR;     // 8 tiles/batch
constexpr int TRW   = TR * W;     // 15360 targets/tile (u32 LDS = 61440 B)
constexpr int WBLK  = B * TILES;  // 96 winner blocks
constexpr int CGRID = WBLK + GRID; // kBW grid

// ws layout: redA[GRID*4] f32 @ +0 (8 KB) | redB[GRID*2] f32 @ +8192 (4 KB) |
//            coords[BHW] u32 @ +16384 (5.90 MB) | win[BHW] u32 @ +16384+BHW*4
// Winner semantics: LWW in linear index order == max-index-wins (proven
// bit-exact). Scatter transport = LDS atomicMax per tile (u32 key = n_local+1,
// 0 = no writer); winner blocks overwrite their whole win[] slice, so no
// pre-zeroing pass. coords[] packs the (clipped, rintf-rounded) target as
// (cyi<<10)|cxi so the 8 tile-scans re-read 4 B/src (L2-hot) instead of 8 B.
// check[] scratch lives in out[0..BHW) between kBW and kC (proven pattern).

// P = (K @ pose)[:3,:] — arithmetic identical to reference einsum
// (left-assoc, contract off).
__device__ __forceinline__ void computeP(const float* __restrict__ Kb,
                                         const float* __restrict__ Po, float* P) {
#pragma unroll
    for (int i = 0; i < 3; ++i)
#pragma unroll
        for (int j = 0; j < 4; ++j) {
            float s = Kb[i*4+0] * Po[0*4+j];
            s = s + Kb[i*4+1] * Po[1*4+j];
            s = s + Kb[i*4+2] * Po[2*4+j];
            s = s + Kb[i*4+3] * Po[3*4+j];
            P[i*4+j] = s;
        }
}

__device__ __forceinline__ void static_flow_P(
    const float* __restrict__ iK, const float* __restrict__ P,
    int x, int y, float d, float& sx, float& sy)
{
    float fx = (float)x, fy = (float)y;
    float cam0 = iK[0]*fx + iK[1]*fy + iK[2];
    float cam1 = iK[4]*fx + iK[5]*fy + iK[6];
    float cam2 = iK[8]*fx + iK[9]*fy + iK[10];
    cam0 = d * cam0; cam1 = d * cam1; cam2 = d * cam2;
    float cp0 = P[0]*cam0 + P[1]*cam1 + P[2]*cam2  + P[3];
    float cp1 = P[4]*cam0 + P[5]*cam1 + P[6]*cam2  + P[7];
    float cp2 = P[8]*cam0 + P[9]*cam1 + P[10]*cam2 + P[11];
    float pz = cp2 + EPS;
    sx = cp0 / pz - fx;
    sy = cp1 / pz - fy;
}

__device__ __forceinline__ float norm01(float v, float mn, float mx) {
    return (2.0f * (v - mn)) / (mx - mn) - 1.0f;
}

// Block-wide reduce for 1024-thread blocks (16 waves) + broadcast.
__device__ __forceinline__ void blockRed4(float& a0, float& a1, float& a2, float& a3,
                                          float (*sred)[4], float* bc) {
    for (int off = 32; off; off >>= 1) {
        a0 = fminf(a0, __shfl_down(a0, off, 64));
        a1 = fmaxf(a1, __shfl_down(a1, off, 64));
        a2 = fminf(a2, __shfl_down(a2, off, 64));
        a3 = fmaxf(a3, __shfl_down(a3, off, 64));
    }
    int lane = threadIdx.x & 63, wv = threadIdx.x >> 6;
    if (lane == 0) { sred[wv][0]=a0; sred[wv][1]=a1; sred[wv][2]=a2; sred[wv][3]=a3; }
    __syncthreads();
    if (threadIdx.x == 0) {
#pragma unroll
        for (int w = 1; w < 16; ++w) {
            a0 = fminf(a0, sred[w][0]); a1 = fmaxf(a1, sred[w][1]);
            a2 = fminf(a2, sred[w][2]); a3 = fmaxf(a3, sred[w][3]);
        }
        bc[0]=a0; bc[1]=a1; bc[2]=a2; bc[3]=a3;
    }
    __syncthreads();
    a0=bc[0]; a1=bc[1]; a2=bc[2]; a3=bc[3];
}

__device__ __forceinline__ void blockRed2(float& a0, float& a1,
                                          float (*sred)[4], float* bc) {
    for (int off = 32; off; off >>= 1) {
        a0 = fminf(a0, __shfl_down(a0, off, 64));
        a1 = fmaxf(a1, __shfl_down(a1, off, 64));
    }
    int lane = threadIdx.x & 63, wv = threadIdx.x >> 6;
    if (lane == 0) { sred[wv][0]=a0; sred[wv][1]=a1; }
    __syncthreads();
    if (threadIdx.x == 0) {
#pragma unroll
        for (int w = 1; w < 16; ++w) {
            a0 = fminf(a0, sred[w][0]); a1 = fmaxf(a1, sred[w][1]);
        }
        bc[0]=a0; bc[1]=a1;
    }
    __syncthreads();
    a0=bc[0]; a1=bc[1];
}

// Dispatch 1: single pass over flow+depth — flow min/max + static-flow min/max
// partials into redA; emit packed target coords (u32) for the winner scan.
__global__ void __launch_bounds__(TPB)
kA(const float* __restrict__ flow, const float* __restrict__ depth,
   const float* __restrict__ Km, const float* __restrict__ invK,
   const float* __restrict__ pose,
   unsigned int* __restrict__ coords, float* __restrict__ redA)
{
    __shared__ float sred[16][4];
    __shared__ float bc[4];

    float fmn = INFINITY, fmx = -INFINITY, smn = INFINITY, smx = -INFINITY;
    float P[12]; int bCur = -1;
    const int stride = GRID * TPB;
    for (int g = blockIdx.x * TPB + threadIdx.x; g < NQ; g += stride) {
        int p0 = g * 4;
        int b  = p0 / HW;
        if (b != bCur) { computeP(Km + b*16, pose + b*16, P); bCur = b; }
        const float* iK = invK + b * 16;
        int n0 = p0 - b * HW;
        int y  = n0 / W;                 // quads never cross a row (W%4==0)
        int x0 = n0 - y * W;
        float4 fx4 = *(const float4*)(flow + b*2*HW + n0);
        float4 fy4 = *(const float4*)(flow + b*2*HW + HW + n0);
        float4 d4  = *(const float4*)(depth + p0);
        fmn = fminf(fmn, fminf(fminf(fx4.x, fx4.y), fminf(fx4.z, fx4.w)));
        fmx = fmaxf(fmx, fmaxf(fmaxf(fx4.x, fx4.y), fmaxf(fx4.z, fx4.w)));
        fmn = fminf(fmn, fminf(fminf(fy4.x, fy4.y), fminf(fy4.z, fy4.w)));
        fmx = fmaxf(fmx, fmaxf(fmaxf(fy4.x, fy4.y), fmaxf(fy4.z, fy4.w)));
        float fxa[4] = {fx4.x, fx4.y, fx4.z, fx4.w};
        float fya[4] = {fy4.x, fy4.y, fy4.z, fy4.w};
        float da[4]  = {d4.x, d4.y, d4.z, d4.w};
        uint4 cc;
        unsigned* cca = (unsigned*)&cc;
#pragma unroll
        for (int j = 0; j < 4; ++j) {
            float sx, sy;
            static_flow_P(iK, P, x0 + j, y, da[j], sx, sy);
            smn = fminf(smn, fminf(sx, sy));
            smx = fmaxf(smx, fmaxf(sx, sy));
            // target coords: round-half-even (rintf == jnp.round), clip
            int cxi = (int)rintf((float)(x0 + j) + fxa[j]);
            int cyi = (int)rintf((float)y + fya[j]);
            cxi = min(max(cxi, 0), W - 1);
            cyi = min(max(cyi, 0), H - 1);
            cca[j] = ((unsigned)cyi << 10) | (unsigned)cxi;
        }
        *(uint4*)(coords + p0) = cc;
    }
    blockRed4(fmn, fmx, smn, smx, sred, bc);
    if (threadIdx.x == 0) {
        redA[blockIdx.x*4+0] = fmn; redA[blockIdx.x*4+1] = fmx;
        redA[blockIdx.x*4+2] = smn; redA[blockIdx.x*4+3] = smx;
    }
}

// Dispatch 2, block-specialized:
//  blocks [0,WBLK): winner blocks — scan this batch's coords (L2-hot, shared
//    by 8 tile-blocks), LDS atomicMax(key = n_local+1), write win[] slice.
//  blocks [WBLK, WBLK+GRID): check pass — re-reduce redA, compute check,
//    stash into out[0..BHW), partial min/max -> redB.
__global__ void __launch_bounds__(TPB)
kBW(const float* __restrict__ flow, const float* __restrict__ depth,
    const float* __restrict__ Km, const float* __restrict__ invK,
    const float* __restrict__ pose,
    const unsigned int* __restrict__ coords,
    const float* __restrict__ redA, float* __restrict__ redB,
    unsigned int* __restrict__ win_g, float* __restrict__ out)
{
    __shared__ unsigned int smem[TRW];          // 61440 B -> 2 blocks/CU
    if (blockIdx.x < WBLK) {
        // ---- winner block ----
        const int b    = blockIdx.x / TILES;
        const int tile = blockIdx.x - b * TILES;
        const unsigned t0 = (unsigned)(tile * TR);

        for (int i = threadIdx.x; i < TRW; i += TPB) smem[i] = 0u;
        __syncthreads();

        const uint4* cb = (const uint4*)(coords + b * HW);
        for (int q = threadIdx.x; q < HW / 4; q += TPB) {
            uint4 c4 = cb[q];
            unsigned ca[4] = {c4.x, c4.y, c4.z, c4.w};
            int n0 = q * 4;
#pragma unroll
            for (int j = 0; j < 4; ++j) {
                unsigned r = (ca[j] >> 10) - t0;     // unsigned wrap filter
                if (r < (unsigned)TR)
                    atomicMax(&smem[r * W + (ca[j] & 1023u)],
                              (unsigned)(n0 + j + 1));
            }
        }
        __syncthreads();
        unsigned int* dst = win_g + b * HW + (int)t0 * W;
        for (int i = threadIdx.x; i < TRW; i += TPB)
            dst[i] = smem[i];
        return;
    }

    // ---- check block ----
    float (*sred)[4] = (float(*)[4])smem;
    float* bc = (float*)(smem + 64);

    float gfmn = INFINITY, gfmx = -INFINITY, gsmn = INFINITY, gsmx = -INFINITY;
    for (int i = threadIdx.x; i < GRID; i += TPB) {
        gfmn = fminf(gfmn, redA[i*4+0]); gfmx = fmaxf(gfmx, redA[i*4+1]);
        gsmn = fminf(gsmn, redA[i*4+2]); gsmx = fmaxf(gsmx, redA[i*4+3]);
    }
    blockRed4(gfmn, gfmx, gsmn, gsmx, sred, bc);

    float cmn = INFINITY, cmx = -INFINITY;
    float P[12]; int bCur = -1;
    const int cb = blockIdx.x - WBLK;
    const int stride = GRID * TPB;
    for (int g = cb * TPB + threadIdx.x; g < NQ; g += stride) {
        int p0 = g * 4;
        int b  = p0 / HW;
        if (b != bCur) { computeP(Km + b*16, pose + b*16, P); bCur = b; }
        const float* iK = invK + b * 16;
        int n0 = p0 - b * HW;
        int y  = n0 / W;
        int x0 = n0 - y * W;
        float4 fx4 = *(const float4*)(flow + b*2*HW + n0);
        float4 fy4 = *(const float4*)(flow + b*2*HW + HW + n0);
        float4 d4  = *(const float4*)(depth + p0);
        float fxa[4] = {fx4.x, fx4.y, fx4.z, fx4.w};
        float fya[4] = {fy4.x, fy4.y, fy4.z, fy4.w};
        float da[4]  = {d4.x, d4.y, d4.z, d4.w};
        float4 cv;
        float* cva = (float*)&cv;
#pragma unroll
        for (int j = 0; j < 4; ++j) {
            float sx, sy;
            static_flow_P(iK, P, x0 + j, y, da[j], sx, sy);
            float dx = norm01(fxa[j], gfmn, gfmx) - norm01(sx, gsmn, gsmx);
            float dy = norm01(fya[j], gfmn, gfmx) - norm01(sy, gsmn, gsmx);
            float c = sqrtf(dx*dx + dy*dy);
            cva[j] = c;
            cmn = fminf(cmn, c); cmx = fmaxf(cmx, c);
        }
        *(float4*)(out + p0) = cv;   // stash check (overwritten by kC)
    }
    blockRed2(cmn, cmx, sred, bc);
    if (threadIdx.x == 0) { redB[cb*2] = cmn; redB[cb*2+1] = cmx; }
}

// Dispatch 3: re-reduce redB + threshold stashed check in-place + winner
// gather (exact payloads) -> bwd_flow, seg_ref.
__global__ void __launch_bounds__(TPB)
kC(const float* __restrict__ flow, const int* __restrict__ seg,
   const float* __restrict__ redB, const unsigned int* __restrict__ win,
   float* __restrict__ out)
{
    __shared__ float sred[16][4];
    __shared__ float bc[4];

    float gcmn = INFINITY, gcmx = -INFINITY;
    for (int i = threadIdx.x; i < GRID; i += TPB) {
        gcmn = fminf(gcmn, redB[2*i]); gcmx = fmaxf(gcmx, redB[2*i+1]);
    }
    blockRed2(gcmn, gcmx, sred, bc);

    const int stride = GRID * TPB;
    for (int g = blockIdx.x * TPB + threadIdx.x; g < NQ; g += stride) {
        int p0 = g * 4;
        int b  = p0 / HW;
        int n0 = p0 - b * HW;
        float4 c4 = *(const float4*)(out + p0);     // stashed check
        uint4  w4 = *(const uint4*)(win + p0);
        const float* fb = flow + b * 2 * HW;
        const int*   sb = seg + b * HW;
        float    ca[4] = {c4.x, c4.y, c4.z, c4.w};
        unsigned wa[4] = {w4.x, w4.y, w4.z, w4.w};
        float4 m4, bx4, by4, sg4;
        float* ma  = (float*)&m4;
        float* bxa = (float*)&bx4;
        float* bya = (float*)&by4;
        float* sga = (float*)&sg4;
#pragma unroll
        for (int j = 0; j < 4; ++j) {
            float cn = (ca[j] - gcmn) / (gcmx - gcmn);
            ma[j] = (cn < 0.98f) ? 1.0f : 0.0f;
            float bx = 0.0f, by = 0.0f, sg = 0.0f;
            if (wa[j]) {
                int nw = (int)wa[j] - 1;
                bx = -fb[nw];
                by = -fb[HW + nw];
                sg = sb[nw] ? 1.0f : 0.0f;
            }
            bxa[j] = bx; bya[j] = by; sga[j] = sg;
        }
        *(float4*)(out + p0)                      = m4;   // motion_mask
        *(float4*)(out + BHW + b*2*HW + n0)       = bx4;  // bwd_flow x
        *(float4*)(out + BHW + b*2*HW + HW + n0)  = by4;  // bwd_flow y
        *(float4*)(out + 3*BHW + p0)              = sg4;  // seg_ref
    }
}

} // namespace

extern "C" void kernel_launch(void* const* d_in, const int* in_sizes, int n_in,
                              void* d_out, int out_size, void* d_ws, size_t ws_size,
                              hipStream_t stream) {
    const float* flow  = (const float*)d_in[0];
    const float* depth = (const float*)d_in[1];
    const float* Km    = (const float*)d_in[2];
    const float* invK  = (const float*)d_in[3];
    const float* pose  = (const float*)d_in[4];
    const int*   seg   = (const int*)d_in[5];
    float* out = (float*)d_out;

    float* redA = (float*)d_ws;
    float* redB = (float*)((char*)d_ws + 8192);
    unsigned int* coords = (unsigned int*)((char*)d_ws + 16384);           // 5.90 MB
    unsigned int* win    = coords + BHW;                                   // 5.90 MB

    kA <<<GRID,  TPB, 0, stream>>>(flow, depth, Km, invK, pose, coords, redA);
    kBW<<<CGRID, TPB, 0, stream>>>(flow, depth, Km, invK, pose, coords,
                                   redA, redB, win, out);
    kC <<<GRID,  TPB, 0, stream>>>(flow, seg, redB, win, out);
}

// Round 4
// 142.536 us; speedup vs baseline: 1.3090x; 1.0534x over previous
//
#include <hip/hip_runtime.h>
#include <math.h>

// Match numpy (no FMA contraction) — mask boundary is bit-sensitive.
#pragma clang fp contract(off)

namespace {

constexpr int B = 12, H = 192, W = 640;
constexpr int HW  = H * W;        // 122880
constexpr int BHW = B * HW;       // 1474560
constexpr int NQ  = BHW / 4;      // 368640 float4 groups
constexpr float EPS = 1e-7f;

// kA / kM: 256-thread blocks, exactly one quad per thread, one generation.
constexpr int TA = 256;
constexpr int GA = NQ / TA;       // 1440 blocks

constexpr int TR    = 24;         // winner-tile rows
constexpr int TILES = H / TR;     // 8 tiles/batch
constexpr int TRW   = TR * W;     // 15360 targets/tile (u32 LDS = 61440 B)
constexpr int GW    = B * TILES;  // 96 winner blocks
constexpr int GC    = 416;        // check blocks  (GW+GC = 512 = 2/CU exactly)
constexpr int CGRID = GW + GC;
constexpr int TPB   = 1024;

// ws layout: redA[GA*4] f32 @ +0 (23 KB) | redB[GC*2] f32 @ +24576 |
//            coords[BHW] u32 @ +32768 (5.90 MB).  (win[] eliminated — the
//            winner tile is consumed in-LDS by the same block.)
// Winner semantics: LWW in linear index order == max-index-wins (proven
// bit-exact). coords[] packs the clipped, rintf-rounded target as
// (cyi<<10)|cxi; winner key = batch-local n+1, 0 = no writer.
// check[] scratch lives in out[0..BHW) between kBW and kM (proven pattern).

// P = (K @ pose)[:3,:] — arithmetic identical to reference einsum
// (left-assoc, contract off).
__device__ __forceinline__ void computeP(const float* __restrict__ Kb,
                                         const float* __restrict__ Po, float* P) {
#pragma unroll
    for (int i = 0; i < 3; ++i)
#pragma unroll
        for (int j = 0; j < 4; ++j) {
            float s = Kb[i*4+0] * Po[0*4+j];
            s = s + Kb[i*4+1] * Po[1*4+j];
            s = s + Kb[i*4+2] * Po[2*4+j];
            s = s + Kb[i*4+3] * Po[3*4+j];
            P[i*4+j] = s;
        }
}

__device__ __forceinline__ void static_flow_P(
    const float* __restrict__ iK, const float* __restrict__ P,
    int x, int y, float d, float& sx, float& sy)
{
    float fx = (float)x, fy = (float)y;
    float cam0 = iK[0]*fx + iK[1]*fy + iK[2];
    float cam1 = iK[4]*fx + iK[5]*fy + iK[6];
    float cam2 = iK[8]*fx + iK[9]*fy + iK[10];
    cam0 = d * cam0; cam1 = d * cam1; cam2 = d * cam2;
    float cp0 = P[0]*cam0 + P[1]*cam1 + P[2]*cam2  + P[3];
    float cp1 = P[4]*cam0 + P[5]*cam1 + P[6]*cam2  + P[7];
    float cp2 = P[8]*cam0 + P[9]*cam1 + P[10]*cam2 + P[11];
    float pz = cp2 + EPS;
    sx = cp0 / pz - fx;
    sy = cp1 / pz - fy;
}

__device__ __forceinline__ float norm01(float v, float mn, float mx) {
    return (2.0f * (v - mn)) / (mx - mn) - 1.0f;
}

// Block-wide min/max reduce + broadcast, parameterized on wave count.
template<int NW>
__device__ __forceinline__ void blockRed4T(float& a0, float& a1, float& a2, float& a3,
                                           float (*sred)[4], float* bc) {
    for (int off = 32; off; off >>= 1) {
        a0 = fminf(a0, __shfl_down(a0, off, 64));
        a1 = fmaxf(a1, __shfl_down(a1, off, 64));
        a2 = fminf(a2, __shfl_down(a2, off, 64));
        a3 = fmaxf(a3, __shfl_down(a3, off, 64));
    }
    int lane = threadIdx.x & 63, wv = threadIdx.x >> 6;
    if (lane == 0) { sred[wv][0]=a0; sred[wv][1]=a1; sred[wv][2]=a2; sred[wv][3]=a3; }
    __syncthreads();
    if (threadIdx.x == 0) {
#pragma unroll
        for (int w = 1; w < NW; ++w) {
            a0 = fminf(a0, sred[w][0]); a1 = fmaxf(a1, sred[w][1]);
            a2 = fminf(a2, sred[w][2]); a3 = fmaxf(a3, sred[w][3]);
        }
        bc[0]=a0; bc[1]=a1; bc[2]=a2; bc[3]=a3;
    }
    __syncthreads();
    a0=bc[0]; a1=bc[1]; a2=bc[2]; a3=bc[3];
}

template<int NW>
__device__ __forceinline__ void blockRed2T(float& a0, float& a1,
                                           float (*sred)[4], float* bc) {
    for (int off = 32; off; off >>= 1) {
        a0 = fminf(a0, __shfl_down(a0, off, 64));
        a1 = fmaxf(a1, __shfl_down(a1, off, 64));
    }
    int lane = threadIdx.x & 63, wv = threadIdx.x >> 6;
    if (lane == 0) { sred[wv][0]=a0; sred[wv][1]=a1; }
    __syncthreads();
    if (threadIdx.x == 0) {
#pragma unroll
        for (int w = 1; w < NW; ++w) {
            a0 = fminf(a0, sred[w][0]); a1 = fmaxf(a1, sred[w][1]);
        }
        bc[0]=a0; bc[1]=a1;
    }
    __syncthreads();
    a0=bc[0]; a1=bc[1];
}

// Dispatch 1: one quad/thread — flow min/max + static-flow min/max partials
// into redA; emit packed target coords (u32) for the winner scan.
__global__ void __launch_bounds__(TA)
kA(const float* __restrict__ flow, const float* __restrict__ depth,
   const float* __restrict__ Km, const float* __restrict__ invK,
   const float* __restrict__ pose,
   unsigned int* __restrict__ coords, float* __restrict__ redA)
{
    __shared__ float sred[4][4];
    __shared__ float bc[4];

    int g  = blockIdx.x * TA + threadIdx.x;       // < NQ by construction
    int p0 = g * 4;
    int b  = p0 / HW;
    float P[12];
    computeP(Km + b*16, pose + b*16, P);
    const float* iK = invK + b * 16;
    int n0 = p0 - b * HW;
    int y  = n0 / W;                 // quads never cross a row (W%4==0)
    int x0 = n0 - y * W;
    float4 fx4 = *(const float4*)(flow + b*2*HW + n0);
    float4 fy4 = *(const float4*)(flow + b*2*HW + HW + n0);
    float4 d4  = *(const float4*)(depth + p0);
    float fmn = fminf(fminf(fx4.x, fx4.y), fminf(fx4.z, fx4.w));
    float fmx = fmaxf(fmaxf(fx4.x, fx4.y), fmaxf(fx4.z, fx4.w));
    fmn = fminf(fmn, fminf(fminf(fy4.x, fy4.y), fminf(fy4.z, fy4.w)));
    fmx = fmaxf(fmx, fmaxf(fmaxf(fy4.x, fy4.y), fmaxf(fy4.z, fy4.w)));
    float smn = INFINITY, smx = -INFINITY;
    float fxa[4] = {fx4.x, fx4.y, fx4.z, fx4.w};
    float fya[4] = {fy4.x, fy4.y, fy4.z, fy4.w};
    float da[4]  = {d4.x, d4.y, d4.z, d4.w};
    uint4 cc;
    unsigned* cca = (unsigned*)&cc;
#pragma unroll
    for (int j = 0; j < 4; ++j) {
        float sx, sy;
        static_flow_P(iK, P, x0 + j, y, da[j], sx, sy);
        smn = fminf(smn, fminf(sx, sy));
        smx = fmaxf(smx, fmaxf(sx, sy));
        // target coords: round-half-even (rintf == jnp.round), clip
        int cxi = (int)rintf((float)(x0 + j) + fxa[j]);
        int cyi = (int)rintf((float)y + fya[j]);
        cxi = min(max(cxi, 0), W - 1);
        cyi = min(max(cyi, 0), H - 1);
        cca[j] = ((unsigned)cyi << 10) | (unsigned)cxi;
    }
    *(uint4*)(coords + p0) = cc;

    blockRed4T<4>(fmn, fmx, smn, smx, sred, bc);
    if (threadIdx.x == 0) {
        redA[blockIdx.x*4+0] = fmn; redA[blockIdx.x*4+1] = fmx;
        redA[blockIdx.x*4+2] = smn; redA[blockIdx.x*4+3] = smx;
    }
}

// Dispatch 2, block-specialized (512 blocks = one residency generation):
//  blocks [0,GW): winner blocks — scan batch coords (L2-hot), LDS atomicMax,
//    then consume the tile IN-LDS: gather exact payloads, write bwd_flow +
//    seg_ref outputs directly. No win[] round-trip.
//  blocks [GW,GW+GC): check blocks — re-reduce redA, compute check, stash
//    into out[0..BHW), partial min/max -> redB.
__global__ void __launch_bounds__(TPB)
kBW(const float* __restrict__ flow, const float* __restrict__ depth,
    const float* __restrict__ Km, const float* __restrict__ invK,
    const float* __restrict__ pose, const int* __restrict__ seg,
    const unsigned int* __restrict__ coords,
    const float* __restrict__ redA, float* __restrict__ redB,
    float* __restrict__ out)
{
    __shared__ unsigned int smem[TRW];          // 61440 B -> 2 blocks/CU
    if (blockIdx.x < GW) {
        // ---- winner block: scatter then in-LDS gather ----
        const int b    = blockIdx.x / TILES;
        const int tile = blockIdx.x - b * TILES;
        const unsigned t0 = (unsigned)(tile * TR);

        for (int q = threadIdx.x; q < TRW/4; q += TPB)
            *(uint4*)(smem + q*4) = make_uint4(0u,0u,0u,0u);
        __syncthreads();

        const uint4* cb = (const uint4*)(coords + b * HW);
        for (int q = threadIdx.x; q < HW / 4; q += TPB) {
            uint4 c4 = cb[q];
            unsigned ca[4] = {c4.x, c4.y, c4.z, c4.w};
            int n0 = q * 4;
#pragma unroll
            for (int j = 0; j < 4; ++j) {
                unsigned r = (ca[j] >> 10) - t0;     // unsigned wrap filter
                if (r < (unsigned)TR)
                    atomicMax(&smem[r * W + (ca[j] & 1023u)],
                              (unsigned)(n0 + j + 1));
            }
        }
        __syncthreads();

        // in-LDS gather: tile targets n in [t0*W, t0*W+TRW)
        const float* fb = flow + b * 2 * HW;
        const int*   sb = seg + b * HW;
        const int    nbase = (int)t0 * W;
        for (int q = threadIdx.x; q < TRW/4; q += TPB) {
            uint4 w4 = *(const uint4*)(smem + q*4);
            unsigned wa[4] = {w4.x, w4.y, w4.z, w4.w};
            float4 bx4, by4, sg4;
            float* bxa = (float*)&bx4;
            float* bya = (float*)&by4;
            float* sga = (float*)&sg4;
#pragma unroll
            for (int j = 0; j < 4; ++j) {
                float bx = 0.0f, by = 0.0f, sg = 0.0f;
                if (wa[j]) {
                    int nw = (int)wa[j] - 1;
                    bx = -fb[nw];
                    by = -fb[HW + nw];
                    sg = sb[nw] ? 1.0f : 0.0f;
                }
                bxa[j] = bx; bya[j] = by; sga[j] = sg;
            }
            int n = nbase + q * 4;
            *(float4*)(out + BHW + b*2*HW + n)      = bx4;  // bwd_flow x
            *(float4*)(out + BHW + b*2*HW + HW + n) = by4;  // bwd_flow y
            *(float4*)(out + 3*BHW + b*HW + n)      = sg4;  // seg_ref
        }
        return;
    }

    // ---- check block ----
    float (*sred)[4] = (float(*)[4])smem;
    float* bc = (float*)(smem + 64);

    float gfmn = INFINITY, gfmx = -INFINITY, gsmn = INFINITY, gsmx = -INFINITY;
    for (int i = threadIdx.x; i < GA; i += TPB) {
        gfmn = fminf(gfmn, redA[i*4+0]); gfmx = fmaxf(gfmx, redA[i*4+1]);
        gsmn = fminf(gsmn, redA[i*4+2]); gsmx = fmaxf(gsmx, redA[i*4+3]);
    }
    blockRed4T<16>(gfmn, gfmx, gsmn, gsmx, sred, bc);

    float cmn = INFINITY, cmx = -INFINITY;
    float P[12]; int bCur = -1;
    const int cb = blockIdx.x - GW;
    const int stride = GC * TPB;
    for (int g = cb * TPB + threadIdx.x; g < NQ; g += stride) {
        int p0 = g * 4;
        int b  = p0 / HW;
        if (b != bCur) { computeP(Km + b*16, pose + b*16, P); bCur = b; }
        const float* iK = invK + b * 16;
        int n0 = p0 - b * HW;
        int y  = n0 / W;
        int x0 = n0 - y * W;
        float4 fx4 = *(const float4*)(flow + b*2*HW + n0);
        float4 fy4 = *(const float4*)(flow + b*2*HW + HW + n0);
        float4 d4  = *(const float4*)(depth + p0);
        float fxa[4] = {fx4.x, fx4.y, fx4.z, fx4.w};
        float fya[4] = {fy4.x, fy4.y, fy4.z, fy4.w};
        float da[4]  = {d4.x, d4.y, d4.z, d4.w};
        float4 cv;
        float* cva = (float*)&cv;
#pragma unroll
        for (int j = 0; j < 4; ++j) {
            float sx, sy;
            static_flow_P(iK, P, x0 + j, y, da[j], sx, sy);
            float dx = norm01(fxa[j], gfmn, gfmx) - norm01(sx, gsmn, gsmx);
            float dy = norm01(fya[j], gfmn, gfmx) - norm01(sy, gsmn, gsmx);
            float c = sqrtf(dx*dx + dy*dy);
            cva[j] = c;
            cmn = fminf(cmn, c); cmx = fmaxf(cmx, c);
        }
        *(float4*)(out + p0) = cv;   // stash check (overwritten by kM)
    }
    blockRed2T<16>(cmn, cmx, sred, bc);
    if (threadIdx.x == 0) { redB[cb*2] = cmn; redB[cb*2+1] = cmx; }
}

// Dispatch 3: re-reduce redB + threshold stashed check in-place -> motion_mask.
__global__ void __launch_bounds__(TA)
kM(const float* __restrict__ redB, float* __restrict__ out)
{
    __shared__ float sred[4][4];
    __shared__ float bc[4];

    float gcmn = INFINITY, gcmx = -INFINITY;
    for (int i = threadIdx.x; i < GC; i += TA) {
        gcmn = fminf(gcmn, redB[2*i]); gcmx = fmaxf(gcmx, redB[2*i+1]);
    }
    blockRed2T<4>(gcmn, gcmx, sred, bc);

    int p0 = (blockIdx.x * TA + threadIdx.x) * 4;   // < BHW by construction
    float4 c4 = *(const float4*)(out + p0);          // stashed check
    float ca[4] = {c4.x, c4.y, c4.z, c4.w};
    float4 m4;
    float* ma = (float*)&m4;
#pragma unroll
    for (int j = 0; j < 4; ++j) {
        float cn = (ca[j] - gcmn) / (gcmx - gcmn);
        ma[j] = (cn < 0.98f) ? 1.0f : 0.0f;
    }
    *(float4*)(out + p0) = m4;                       // motion_mask
}

} // namespace

extern "C" void kernel_launch(void* const* d_in, const int* in_sizes, int n_in,
                              void* d_out, int out_size, void* d_ws, size_t ws_size,
                              hipStream_t stream) {
    const float* flow  = (const float*)d_in[0];
    const float* depth = (const float*)d_in[1];
    const float* Km    = (const float*)d_in[2];
    const float* invK  = (const float*)d_in[3];
    const float* pose  = (const float*)d_in[4];
    const int*   seg   = (const int*)d_in[5];
    float* out = (float*)d_out;

    float* redA = (float*)d_ws;                                  // GA*4 f32
    float* redB = (float*)((char*)d_ws + 24576);                 // GC*2 f32
    unsigned int* coords = (unsigned int*)((char*)d_ws + 32768); // 5.90 MB

    kA <<<GA,    TA,  0, stream>>>(flow, depth, Km, invK, pose, coords, redA);
    kBW<<<CGRID, TPB, 0, stream>>>(flow, depth, Km, invK, pose, seg, coords,
                                   redA, redB, out);
    kM <<<GA,    TA,  0, stream>>>(redB, out);
}

// Round 5
// 136.723 us; speedup vs baseline: 1.3647x; 1.0425x over previous
//
#include <hip/hip_runtime.h>
#include <math.h>

// Match numpy (no FMA contraction) — mask boundary is bit-sensitive.
#pragma clang fp contract(off)

namespace {

constexpr int B = 12, H = 192, W = 640;
constexpr int HW  = H * W;        // 122880
constexpr int BHW = B * HW;       // 1474560
constexpr int NQ  = BHW / 4;      // 368640 float4 groups
constexpr float EPS = 1e-7f;

// kA / kM: 256-thread blocks, exactly one quad per thread, one generation.
constexpr int TA = 256;
constexpr int GA = NQ / TA;       // 1440 blocks

constexpr int TR    = 24;         // winner-tile rows
constexpr int TILES = H / TR;     // 8 tiles/batch
constexpr int TRW   = TR * W;     // 15360 targets/tile (u32 LDS = 61440 B)
constexpr int GW    = B * TILES;  // 96 winner blocks
constexpr int GC    = 416;        // check blocks  (GW+GC = 512 = 2/CU exactly)
constexpr int CGRID = GW + GC;
constexpr int TPB   = 1024;

// ws layout: redA[GA*4] f32 @ +0 (23 KB) | redB[GC*2] f32 @ +24576 |
//            coords[BHW] u32 @ +32768 (5.90 MB).
// Winner semantics: LWW in linear index order == max-index-wins (proven
// bit-exact). coords[] packs the clipped, rintf-rounded target as
// (cyi<<10)|cxi; winner key = batch-local n+1, 0 = no writer.
// check[] scratch lives in out[0..BHW) between kBW and kM (proven pattern).
//
// XCD-aware winner mapping (R5): workgroups are dispatched round-robin
// across the 8 XCDs (XCD = blockIdx % 8, per learn_hip m09/m157). The R4
// mapping (batch = bi/8) put a batch's 8 tile-blocks on 8 DIFFERENT XCDs —
// zero L2 sharing, 96 × 491 KB coords re-fetch from HBM (measured: 102 MB
// FETCH, 59.6 µs). Remap: x = bi&7 (XCD), k = bi>>3, w' = x*12+k,
// batch = w'>>3, tile = w'&7. Bijective over [0,96); each batch spans ≤2
// XCDs, so its coords slice is HBM-fetched ≤2× and the remaining scans are
// per-XCD L2 hits. Perf heuristic only — any mapping is correct.

// P = (K @ pose)[:3,:] — arithmetic identical to reference einsum
// (left-assoc, contract off).
__device__ __forceinline__ void computeP(const float* __restrict__ Kb,
                                         const float* __restrict__ Po, float* P) {
#pragma unroll
    for (int i = 0; i < 3; ++i)
#pragma unroll
        for (int j = 0; j < 4; ++j) {
            float s = Kb[i*4+0] * Po[0*4+j];
            s = s + Kb[i*4+1] * Po[1*4+j];
            s = s + Kb[i*4+2] * Po[2*4+j];
            s = s + Kb[i*4+3] * Po[3*4+j];
            P[i*4+j] = s;
        }
}

__device__ __forceinline__ void static_flow_P(
    const float* __restrict__ iK, const float* __restrict__ P,
    int x, int y, float d, float& sx, float& sy)
{
    float fx = (float)x, fy = (float)y;
    float cam0 = iK[0]*fx + iK[1]*fy + iK[2];
    float cam1 = iK[4]*fx + iK[5]*fy + iK[6];
    float cam2 = iK[8]*fx + iK[9]*fy + iK[10];
    cam0 = d * cam0; cam1 = d * cam1; cam2 = d * cam2;
    float cp0 = P[0]*cam0 + P[1]*cam1 + P[2]*cam2  + P[3];
    float cp1 = P[4]*cam0 + P[5]*cam1 + P[6]*cam2  + P[7];
    float cp2 = P[8]*cam0 + P[9]*cam1 + P[10]*cam2 + P[11];
    float pz = cp2 + EPS;
    sx = cp0 / pz - fx;
    sy = cp1 / pz - fy;
}

__device__ __forceinline__ float norm01(float v, float mn, float mx) {
    return (2.0f * (v - mn)) / (mx - mn) - 1.0f;
}

// Block-wide min/max reduce + broadcast, parameterized on wave count.
template<int NW>
__device__ __forceinline__ void blockRed4T(float& a0, float& a1, float& a2, float& a3,
                                           float (*sred)[4], float* bc) {
    for (int off = 32; off; off >>= 1) {
        a0 = fminf(a0, __shfl_down(a0, off, 64));
        a1 = fmaxf(a1, __shfl_down(a1, off, 64));
        a2 = fminf(a2, __shfl_down(a2, off, 64));
        a3 = fmaxf(a3, __shfl_down(a3, off, 64));
    }
    int lane = threadIdx.x & 63, wv = threadIdx.x >> 6;
    if (lane == 0) { sred[wv][0]=a0; sred[wv][1]=a1; sred[wv][2]=a2; sred[wv][3]=a3; }
    __syncthreads();
    if (threadIdx.x == 0) {
#pragma unroll
        for (int w = 1; w < NW; ++w) {
            a0 = fminf(a0, sred[w][0]); a1 = fmaxf(a1, sred[w][1]);
            a2 = fminf(a2, sred[w][2]); a3 = fmaxf(a3, sred[w][3]);
        }
        bc[0]=a0; bc[1]=a1; bc[2]=a2; bc[3]=a3;
    }
    __syncthreads();
    a0=bc[0]; a1=bc[1]; a2=bc[2]; a3=bc[3];
}

template<int NW>
__device__ __forceinline__ void blockRed2T(float& a0, float& a1,
                                           float (*sred)[4], float* bc) {
    for (int off = 32; off; off >>= 1) {
        a0 = fminf(a0, __shfl_down(a0, off, 64));
        a1 = fmaxf(a1, __shfl_down(a1, off, 64));
    }
    int lane = threadIdx.x & 63, wv = threadIdx.x >> 6;
    if (lane == 0) { sred[wv][0]=a0; sred[wv][1]=a1; }
    __syncthreads();
    if (threadIdx.x == 0) {
#pragma unroll
        for (int w = 1; w < NW; ++w) {
            a0 = fminf(a0, sred[w][0]); a1 = fmaxf(a1, sred[w][1]);
        }
        bc[0]=a0; bc[1]=a1;
    }
    __syncthreads();
    a0=bc[0]; a1=bc[1];
}

// Dispatch 1: one quad/thread — flow min/max + static-flow min/max partials
// into redA; emit packed target coords (u32) for the winner scan.
__global__ void __launch_bounds__(TA)
kA(const float* __restrict__ flow, const float* __restrict__ depth,
   const float* __restrict__ Km, const float* __restrict__ invK,
   const float* __restrict__ pose,
   unsigned int* __restrict__ coords, float* __restrict__ redA)
{
    __shared__ float sred[4][4];
    __shared__ float bc[4];

    int g  = blockIdx.x * TA + threadIdx.x;       // < NQ by construction
    int p0 = g * 4;
    int b  = p0 / HW;
    float P[12];
    computeP(Km + b*16, pose + b*16, P);
    const float* iK = invK + b * 16;
    int n0 = p0 - b * HW;
    int y  = n0 / W;                 // quads never cross a row (W%4==0)
    int x0 = n0 - y * W;
    float4 fx4 = *(const float4*)(flow + b*2*HW + n0);
    float4 fy4 = *(const float4*)(flow + b*2*HW + HW + n0);
    float4 d4  = *(const float4*)(depth + p0);
    float fmn = fminf(fminf(fx4.x, fx4.y), fminf(fx4.z, fx4.w));
    float fmx = fmaxf(fmaxf(fx4.x, fx4.y), fmaxf(fx4.z, fx4.w));
    fmn = fminf(fmn, fminf(fminf(fy4.x, fy4.y), fminf(fy4.z, fy4.w)));
    fmx = fmaxf(fmx, fmaxf(fmaxf(fy4.x, fy4.y), fmaxf(fy4.z, fy4.w)));
    float smn = INFINITY, smx = -INFINITY;
    float fxa[4] = {fx4.x, fx4.y, fx4.z, fx4.w};
    float fya[4] = {fy4.x, fy4.y, fy4.z, fy4.w};
    float da[4]  = {d4.x, d4.y, d4.z, d4.w};
    uint4 cc;
    unsigned* cca = (unsigned*)&cc;
#pragma unroll
    for (int j = 0; j < 4; ++j) {
        float sx, sy;
        static_flow_P(iK, P, x0 + j, y, da[j], sx, sy);
        smn = fminf(smn, fminf(sx, sy));
        smx = fmaxf(smx, fmaxf(sx, sy));
        // target coords: round-half-even (rintf == jnp.round), clip
        int cxi = (int)rintf((float)(x0 + j) + fxa[j]);
        int cyi = (int)rintf((float)y + fya[j]);
        cxi = min(max(cxi, 0), W - 1);
        cyi = min(max(cyi, 0), H - 1);
        cca[j] = ((unsigned)cyi << 10) | (unsigned)cxi;
    }
    *(uint4*)(coords + p0) = cc;

    blockRed4T<4>(fmn, fmx, smn, smx, sred, bc);
    if (threadIdx.x == 0) {
        redA[blockIdx.x*4+0] = fmn; redA[blockIdx.x*4+1] = fmx;
        redA[blockIdx.x*4+2] = smn; redA[blockIdx.x*4+3] = smx;
    }
}

// Dispatch 2, block-specialized (512 blocks = one residency generation):
//  blocks [0,GW): winner blocks (XCD-swizzled batch/tile mapping) — scan
//    batch coords (L2-hot within XCD), LDS atomicMax, then consume the tile
//    IN-LDS: gather exact payloads, write bwd_flow + seg_ref directly.
//  blocks [GW,GW+GC): check blocks — re-reduce redA, compute check, stash
//    into out[0..BHW), partial min/max -> redB.
__global__ void __launch_bounds__(TPB)
kBW(const float* __restrict__ flow, const float* __restrict__ depth,
    const float* __restrict__ Km, const float* __restrict__ invK,
    const float* __restrict__ pose, const int* __restrict__ seg,
    const unsigned int* __restrict__ coords,
    const float* __restrict__ redA, float* __restrict__ redB,
    float* __restrict__ out)
{
    __shared__ unsigned int smem[TRW];          // 61440 B -> 2 blocks/CU
    if (blockIdx.x < GW) {
        // ---- winner block: scatter then in-LDS gather ----
        // XCD-aware mapping: keep a batch's tile-blocks on the same XCD.
        const int x  = blockIdx.x & 7;          // XCD under round-robin model
        const int k  = blockIdx.x >> 3;         // 0..11
        const int wp = x * 12 + k;              // bijective [0,96)
        const int b    = wp >> 3;
        const int tile = wp & 7;
        const unsigned t0 = (unsigned)(tile * TR);

        for (int q = threadIdx.x; q < TRW/4; q += TPB)
            *(uint4*)(smem + q*4) = make_uint4(0u,0u,0u,0u);
        __syncthreads();

        const uint4* cb = (const uint4*)(coords + b * HW);
        for (int q = threadIdx.x; q < HW / 4; q += TPB) {
            uint4 c4 = cb[q];
            unsigned ca[4] = {c4.x, c4.y, c4.z, c4.w};
            int n0 = q * 4;
#pragma unroll
            for (int j = 0; j < 4; ++j) {
                unsigned r = (ca[j] >> 10) - t0;     // unsigned wrap filter
                if (r < (unsigned)TR)
                    atomicMax(&smem[r * W + (ca[j] & 1023u)],
                              (unsigned)(n0 + j + 1));
            }
        }
        __syncthreads();

        // in-LDS gather: tile targets n in [t0*W, t0*W+TRW)
        const float* fb = flow + b * 2 * HW;
        const int*   sb = seg + b * HW;
        const int    nbase = (int)t0 * W;
        for (int q = threadIdx.x; q < TRW/4; q += TPB) {
            uint4 w4 = *(const uint4*)(smem + q*4);
            unsigned wa[4] = {w4.x, w4.y, w4.z, w4.w};
            float4 bx4, by4, sg4;
            float* bxa = (float*)&bx4;
            float* bya = (float*)&by4;
            float* sga = (float*)&sg4;
#pragma unroll
            for (int j = 0; j < 4; ++j) {
                float bx = 0.0f, by = 0.0f, sg = 0.0f;
                if (wa[j]) {
                    int nw = (int)wa[j] - 1;
                    bx = -fb[nw];
                    by = -fb[HW + nw];
                    sg = sb[nw] ? 1.0f : 0.0f;
                }
                bxa[j] = bx; bya[j] = by; sga[j] = sg;
            }
            int n = nbase + q * 4;
            *(float4*)(out + BHW + b*2*HW + n)      = bx4;  // bwd_flow x
            *(float4*)(out + BHW + b*2*HW + HW + n) = by4;  // bwd_flow y
            *(float4*)(out + 3*BHW + b*HW + n)      = sg4;  // seg_ref
        }
        return;
    }

    // ---- check block ----
    float (*sred)[4] = (float(*)[4])smem;
    float* bc = (float*)(smem + 64);

    float gfmn = INFINITY, gfmx = -INFINITY, gsmn = INFINITY, gsmx = -INFINITY;
    for (int i = threadIdx.x; i < GA; i += TPB) {
        gfmn = fminf(gfmn, redA[i*4+0]); gfmx = fmaxf(gfmx, redA[i*4+1]);
        gsmn = fminf(gsmn, redA[i*4+2]); gsmx = fmaxf(gsmx, redA[i*4+3]);
    }
    blockRed4T<16>(gfmn, gfmx, gsmn, gsmx, sred, bc);

    float cmn = INFINITY, cmx = -INFINITY;
    float P[12]; int bCur = -1;
    const int cb = blockIdx.x - GW;
    const int stride = GC * TPB;
    for (int g = cb * TPB + threadIdx.x; g < NQ; g += stride) {
        int p0 = g * 4;
        int b  = p0 / HW;
        if (b != bCur) { computeP(Km + b*16, pose + b*16, P); bCur = b; }
        const float* iK = invK + b * 16;
        int n0 = p0 - b * HW;
        int y  = n0 / W;
        int x0 = n0 - y * W;
        float4 fx4 = *(const float4*)(flow + b*2*HW + n0);
        float4 fy4 = *(const float4*)(flow + b*2*HW + HW + n0);
        float4 d4  = *(const float4*)(depth + p0);
        float fxa[4] = {fx4.x, fx4.y, fx4.z, fx4.w};
        float fya[4] = {fy4.x, fy4.y, fy4.z, fy4.w};
        float da[4]  = {d4.x, d4.y, d4.z, d4.w};
        float4 cv;
        float* cva = (float*)&cv;
#pragma unroll
        for (int j = 0; j < 4; ++j) {
            float sx, sy;
            static_flow_P(iK, P, x0 + j, y, da[j], sx, sy);
            float dx = norm01(fxa[j], gfmn, gfmx) - norm01(sx, gsmn, gsmx);
            float dy = norm01(fya[j], gfmn, gfmx) - norm01(sy, gsmn, gsmx);
            float c = sqrtf(dx*dx + dy*dy);
            cva[j] = c;
            cmn = fminf(cmn, c); cmx = fmaxf(cmx, c);
        }
        *(float4*)(out + p0) = cv;   // stash check (overwritten by kM)
    }
    blockRed2T<16>(cmn, cmx, sred, bc);
    if (threadIdx.x == 0) { redB[cb*2] = cmn; redB[cb*2+1] = cmx; }
}

// Dispatch 3: re-reduce redB + threshold stashed check in-place -> motion_mask.
__global__ void __launch_bounds__(TA)
kM(const float* __restrict__ redB, float* __restrict__ out)
{
    __shared__ float sred[4][4];
    __shared__ float bc[4];

    float gcmn = INFINITY, gcmx = -INFINITY;
    for (int i = threadIdx.x; i < GC; i += TA) {
        gcmn = fminf(gcmn, redB[2*i]); gcmx = fmaxf(gcmx, redB[2*i+1]);
    }
    blockRed2T<4>(gcmn, gcmx, sred, bc);

    int p0 = (blockIdx.x * TA + threadIdx.x) * 4;   // < BHW by construction
    float4 c4 = *(const float4*)(out + p0);          // stashed check
    float ca[4] = {c4.x, c4.y, c4.z, c4.w};
    float4 m4;
    float* ma = (float*)&m4;
#pragma unroll
    for (int j = 0; j < 4; ++j) {
        float cn = (ca[j] - gcmn) / (gcmx - gcmn);
        ma[j] = (cn < 0.98f) ? 1.0f : 0.0f;
    }
    *(float4*)(out + p0) = m4;                       // motion_mask
}

} // namespace

extern "C" void kernel_launch(void* const* d_in, const int* in_sizes, int n_in,
                              void* d_out, int out_size, void* d_ws, size_t ws_size,
                              hipStream_t stream) {
    const float* flow  = (const float*)d_in[0];
    const float* depth = (const float*)d_in[1];
    const float* Km    = (const float*)d_in[2];
    const float* invK  = (const float*)d_in[3];
    const float* pose  = (const float*)d_in[4];
    const int*   seg   = (const int*)d_in[5];
    float* out = (float*)d_out;

    float* redA = (float*)d_ws;                                  // GA*4 f32
    float* redB = (float*)((char*)d_ws + 24576);                 // GC*2 f32
    unsigned int* coords = (unsigned int*)((char*)d_ws + 32768); // 5.90 MB

    kA <<<GA,    TA,  0, stream>>>(flow, depth, Km, invK, pose, coords, redA);
    kBW<<<CGRID, TPB, 0, stream>>>(flow, depth, Km, invK, pose, seg, coords,
                                   redA, redB, out);
    kM <<<GA,    TA,  0, stream>>>(redB, out);
}